// Round 1
// baseline (2516.162 us; speedup 1.0000x reference)
//
#include <hip/hip_runtime.h>

#define BN_SHIFT 7           // 128 nodes per bucket
#define BNODES   128
#define NBMAX    1024        // supports N up to 131072
#define K2_CHUNK 8192        // edges per binmlp block
#define SLOTS    61          // per-node accumulator slots: s1[15] s2[15] s3[15] s4[15] count

__device__ __forceinline__ float leaky(float x) { return fmaxf(x, 0.1f * x); }

// ---------------- K0: coarse bucket histogram (LDS-aggregated) ----------------
__global__ __launch_bounds__(256) void bhist_kernel(const int* __restrict__ src,
                                                    int* __restrict__ bhist, int E, int NB)
{
    __shared__ int h[NBMAX];
    for (int i = threadIdx.x; i < NB; i += 256) h[i] = 0;
    __syncthreads();
    int stride = gridDim.x * 256;
    for (int i = blockIdx.x * 256 + threadIdx.x; i < E; i += stride)
        atomicAdd(&h[src[i] >> BN_SHIFT], 1);
    __syncthreads();
    for (int i = threadIdx.x; i < NB; i += 256) if (h[i]) atomicAdd(&bhist[i], h[i]);
}

// ---------------- K1: scan bucket sizes -> bases ----------------
__global__ __launch_bounds__(64) void bscan_kernel(const int* __restrict__ bhist,
                                                   int* __restrict__ bbase, int E, int NB)
{
    int lane = threadIdx.x;
    int carry = 0;
    for (int base = 0; base < NB; base += 64) {
        int i = base + lane;
        int v = (i < NB) ? bhist[i] : 0;
        int inc = v;
#pragma unroll
        for (int d = 1; d < 64; d <<= 1) { int m = __shfl_up(inc, d); if (lane >= d) inc += m; }
        if (i < NB) bbase[i] = inc - v + carry;
        carry += __shfl(inc, 63);
    }
    if (lane == 0) bbase[NB] = E;
}

// ---------------- K1b: per-sweep cursor reset (sweep-relative bases) ----------------
__global__ __launch_bounds__(256) void breset_kernel(const int* __restrict__ bbase,
                                                     int* __restrict__ bcur, int lo, int hi)
{
    int i = lo + blockIdx.x * 256 + threadIdx.x;
    if (i < hi) bcur[i] = bbase[i] - bbase[lo];
}

// ---------------- K2: fused edge-MLP + bucket binning ----------------
// Reads edge_index/edge_attr COALESCED (original order), gathers x_t (2 MB, L2-resident),
// computes the 15-float message, writes a 64-B payload into the bucket's run.
__global__ __launch_bounds__(512) void binmlp_kernel(
    const int* __restrict__ edge_index, const float* __restrict__ x_t,
    const float* __restrict__ edge_attr,
    const float* __restrict__ w1a, const float* __restrict__ b1a,
    const float* __restrict__ w2a, const float* __restrict__ b2a,
    int* __restrict__ bcur, float* __restrict__ binned,
    int E, int NB, int lo, int hi)
{
    __shared__ int hist[NBMAX];
    __shared__ int cur[NBMAX];
    __shared__ float sw1[240], sw2[240], sb1[16], sb2[16];
    int tid = threadIdx.x;

    for (int i = tid; i < 240; i += 512) {
        int r = i >> 4, c = i & 15;
        sw1[i] = (c < 15) ? w1a[r * 15 + c] : 0.f;
        sw2[i] = (c < 15) ? w2a[r * 15 + c] : 0.f;
    }
    if (tid < 15) { sb1[tid] = b1a[tid]; sb2[tid] = b2a[tid]; }
    for (int i = tid; i < NB; i += 512) hist[i] = 0;

    int cbase = blockIdx.x * K2_CHUNK;
    int n = min(K2_CHUNK, E - cbase);
    __syncthreads();

    // pass 1: chunk histogram (only buckets in this sweep's range)
    for (int i = tid; i < n; i += 512) {
        int b = edge_index[cbase + i] >> BN_SHIFT;
        if (b >= lo && b < hi) atomicAdd(&hist[b], 1);
    }
    __syncthreads();
    // reserve global (sweep-relative) runs: one global atomic per present bucket
    for (int i = tid; i < NB; i += 512) {
        int c = hist[i];
        cur[i] = c ? atomicAdd(&bcur[i], c) : 0;
    }
    __syncthreads();

    // pass 2: compute message + scatter full-line 64-B payload
    for (int i = tid; i < n; i += 512) {
        int s = edge_index[cbase + i];
        int b = s >> BN_SHIFT;
        if (b < lo || b >= hi) continue;
        int t = edge_index[E + cbase + i];

        float in0[15];
        const float* xt = x_t + (size_t)t * 5;
#pragma unroll
        for (int q = 0; q < 5; q++) in0[q] = xt[q];
        const float2* ea = (const float2*)(edge_attr + (size_t)(cbase + i) * 10);
#pragma unroll
        for (int q = 0; q < 5; q++) { float2 t2 = ea[q]; in0[5 + 2 * q] = t2.x; in0[6 + 2 * q] = t2.y; }

        float h[15];
#pragma unroll
        for (int j = 0; j < 15; j++) h[j] = sb1[j];
#pragma unroll
        for (int ii = 0; ii < 15; ii++)
#pragma unroll
            for (int j = 0; j < 15; j++) h[j] = fmaf(in0[ii], sw1[ii * 16 + j], h[j]);
#pragma unroll
        for (int j = 0; j < 15; j++) h[j] = leaky(h[j]);

        float y[15];
#pragma unroll
        for (int j = 0; j < 15; j++) y[j] = sb2[j];
#pragma unroll
        for (int ii = 0; ii < 15; ii++)
#pragma unroll
            for (int j = 0; j < 15; j++) y[j] = fmaf(h[ii], sw2[ii * 16 + j], y[j]);

        int pos = atomicAdd(&cur[b], 1);              // LDS atomic -> unique slot in run
        float4* dst = (float4*)(binned + (size_t)pos * 16);
        dst[0] = make_float4(y[0],  y[1],  y[2],  y[3]);
        dst[1] = make_float4(y[4],  y[5],  y[6],  y[7]);
        dst[2] = make_float4(y[8],  y[9],  y[10], y[11]);
        dst[3] = make_float4(y[12], y[13], y[14], __int_as_float(s & (BNODES - 1)));
    }
}

// ---------------- K3: per-bucket moment accumulation + node MLP ----------------
// One block per 128-node bucket. 4 lanes per edge -> fully coalesced 16-B loads.
// Moments via LDS float atomics into accs[node*61 + slot] (odd stride -> bank spread).
__global__ __launch_bounds__(512) void moment_kernel(
    const float* __restrict__ binned, const int* __restrict__ bbase,
    const float* __restrict__ x_s, const float* __restrict__ u,
    const int* __restrict__ batch_s,
    const float* __restrict__ w1b, const float* __restrict__ b1b,
    const float* __restrict__ w2b, const float* __restrict__ b2b,
    float* __restrict__ out, int N, int lo)
{
    __shared__ float accs[BNODES * SLOTS];     // 31232 B
    __shared__ float o1s[BNODES * 10];         //  5120 B
    __shared__ float tw1[810], tw2[100], tb1[16], tb2[16];
    int tid = threadIdx.x;
    int b = lo + blockIdx.x;
    int node0 = b << BN_SHIFT;

    for (int i = tid; i < 810; i += 512) tw1[i] = w1b[i];
    for (int i = tid; i < 100; i += 512) tw2[i] = w2b[i];
    if (tid < 10) { tb1[tid] = b1b[tid]; tb2[tid] = b2b[tid]; }
    for (int i = tid; i < BNODES * SLOTS; i += 512) accs[i] = 0.f;
    __syncthreads();

    int sweepbase = bbase[lo];
    int lo_e = bbase[b] - sweepbase, hi_e = bbase[b + 1] - sweepbase;

    int q = tid & 3, lane = tid & 63;
    for (int e = lo_e + (tid >> 2); e < hi_e; e += 128) {
        float4 v = *(const float4*)(binned + (size_t)e * 16 + q * 4);
        int nid = __shfl(__float_as_int(v.w), lane | 3);   // node id lives in quad 3's .w
        int ab = nid * SLOTS;
        float vs[4] = {v.x, v.y, v.z, v.w};
#pragma unroll
        for (int j = 0; j < 4; j++) {
            int f = q * 4 + j;
            if (f < 15) {
                float yv = vs[j], y2 = yv * yv;
                atomicAdd(&accs[ab + f],      yv);
                atomicAdd(&accs[ab + 15 + f], y2);
                atomicAdd(&accs[ab + 30 + f], y2 * yv);
                atomicAdd(&accs[ab + 45 + f], y2 * y2);
            }
        }
        if (q == 3) atomicAdd(&accs[ab + 60], 1.0f);
    }
    __syncthreads();

    // finalize moments in place: s1..s4 -> mean, std, skew, kurt
    for (int idx = tid; idx < BNODES * 16; idx += 512) {
        int f = idx & 15, nd = idx >> 4;
        if (f < 15 && node0 + nd < N) {
            int ab = nd * SLOTS;
            float cf  = accs[ab + 60];
            float inv = 1.0f / fmaxf(cf, 1.0f);
            float m1 = accs[ab + f] * inv;
            float m2 = accs[ab + 15 + f] * inv;
            float m3 = accs[ab + 30 + f] * inv;
            float m4 = accs[ab + 45 + f] * inv;
            float var = fmaxf(m2 - m1 * m1, 0.0f);
            float sd  = sqrtf(var + 1e-6f);
            float m1sq = m1 * m1;
            float c3 = m3 - 3.0f * m1 * m2 + 2.0f * m1sq * m1;
            float c4 = m4 - 4.0f * m1 * m3 + 6.0f * m1sq * m2 - 3.0f * m1sq * m1sq;
            float is = 1.0f / sd, is2 = is * is;
            accs[ab + f]      = m1;
            accs[ab + 15 + f] = sd;
            accs[ab + 30 + f] = c3 * is2 * is;
            accs[ab + 45 + f] = c4 * is2 * is2;
        }
    }
    __syncthreads();

    // node MLP layer 1: h[81] -> 10, h = [x_s(10), count, mean(15), std(15), skew(15), kurt(15), u(10)]
    for (int idx = tid; idx < BNODES * 10; idx += 512) {
        int nd = idx / 10, k = idx - nd * 10;
        int node = node0 + nd;
        if (node >= N) continue;
        int ab = nd * SLOTS;
        float acc = tb1[k];
        const float* xs = x_s + (size_t)node * 10;
#pragma unroll
        for (int j = 0; j < 10; j++) acc = fmaf(xs[j], tw1[j * 10 + k], acc);
        acc = fmaf(accs[ab + 60], tw1[100 + k], acc);
#pragma unroll
        for (int f = 0; f < 15; f++) acc = fmaf(accs[ab + f],      tw1[(11 + f) * 10 + k], acc);
#pragma unroll
        for (int f = 0; f < 15; f++) acc = fmaf(accs[ab + 15 + f], tw1[(26 + f) * 10 + k], acc);
#pragma unroll
        for (int f = 0; f < 15; f++) acc = fmaf(accs[ab + 30 + f], tw1[(41 + f) * 10 + k], acc);
#pragma unroll
        for (int f = 0; f < 15; f++) acc = fmaf(accs[ab + 45 + f], tw1[(56 + f) * 10 + k], acc);
        const float* uu = u + (size_t)batch_s[node] * 10;
#pragma unroll
        for (int j = 0; j < 10; j++) acc = fmaf(uu[j], tw1[(71 + j) * 10 + k], acc);
        o1s[idx] = leaky(acc);
    }
    __syncthreads();
    // layer 2 + store
    for (int idx = tid; idx < BNODES * 10; idx += 512) {
        int nd = idx / 10, k = idx - nd * 10;
        int node = node0 + nd;
        if (node >= N) continue;
        float acc = tb2[k];
#pragma unroll
        for (int m = 0; m < 10; m++) acc = fmaf(o1s[nd * 10 + m], tw2[m * 10 + k], acc);
        out[(size_t)node * 10 + k] = acc;
    }
}

extern "C" void kernel_launch(void* const* d_in, const int* in_sizes, int n_in,
                              void* d_out, int out_size, void* d_ws, size_t ws_size,
                              hipStream_t stream)
{
    const float* x_s       = (const float*)d_in[0];
    const float* x_t       = (const float*)d_in[1];
    const float* edge_attr = (const float*)d_in[2];
    const float* u         = (const float*)d_in[3];
    const int*   edge_index= (const int*)d_in[4];
    const int*   batch_s   = (const int*)d_in[5];
    const float* w1a = (const float*)d_in[6];
    const float* b1a = (const float*)d_in[7];
    const float* w2a = (const float*)d_in[8];
    const float* b2a = (const float*)d_in[9];
    const float* w1b = (const float*)d_in[10];
    const float* b1b = (const float*)d_in[11];
    const float* w2b = (const float*)d_in[12];
    const float* b2b = (const float*)d_in[13];

    int N = in_sizes[0] / 10;   // N_S
    int E = in_sizes[2] / 10;   // edge_attr [E,10]
    int NB = (N + BNODES - 1) >> BN_SHIFT;

    // workspace layout (256-B aligned regions)
    char* p = (char*)d_ws;
    auto take = [&](size_t bytes) { char* r = p; p += (bytes + 255) & ~(size_t)255; return r; };
    int* bhist = (int*)take((size_t)NBMAX * 4);
    int* bbase = (int*)take((size_t)(NBMAX + 1) * 4);
    int* bcur  = (int*)take((size_t)NBMAX * 4);
    size_t used  = (size_t)(p - (char*)d_ws);
    size_t avail = (ws_size > used) ? ws_size - used : 0;
    size_t capE  = avail / 64;                 // payload slots that fit
    float* binned = (float*)p;

    // adaptive sweep count: equal-bucket sweeps, ~6% + 16K headroom on Poisson-tight counts
    int S = 1;
    while (S < 64) {
        size_t per = ((size_t)E + S - 1) / (size_t)S;
        if (per + per / 16 + 16384 <= capE) break;
        S++;
    }

    hipMemsetAsync(bhist, 0, (size_t)NB * sizeof(int), stream);
    bhist_kernel<<<512, 256, 0, stream>>>(edge_index, bhist, E, NB);
    bscan_kernel<<<1, 64, 0, stream>>>(bhist, bbase, E, NB);

    int nbps = (NB + S - 1) / S;
    int k2grid = (E + K2_CHUNK - 1) / K2_CHUNK;
    for (int s = 0; s < S; s++) {
        int lo = s * nbps;
        int hi = (lo + nbps < NB) ? lo + nbps : NB;
        if (lo >= hi) break;
        breset_kernel<<<(hi - lo + 255) / 256, 256, 0, stream>>>(bbase, bcur, lo, hi);
        binmlp_kernel<<<k2grid, 512, 0, stream>>>(
            edge_index, x_t, edge_attr, w1a, b1a, w2a, b2a,
            bcur, binned, E, NB, lo, hi);
        moment_kernel<<<hi - lo, 512, 0, stream>>>(
            binned, bbase, x_s, u, batch_s,
            w1b, b1b, w2b, b2b, (float*)d_out, N, lo);
    }
}